// Round 4
// baseline (2372.666 us; speedup 1.0000x reference)
//
#include <hip/hip_runtime.h>

typedef unsigned short u16;
typedef __attribute__((ext_vector_type(8))) __bf16 bf16x8;
typedef __attribute__((ext_vector_type(4))) float f32x4;

typedef __attribute__((address_space(1))) const void gvoid_t;
typedef __attribute__((address_space(3))) void lvoid_t;

enum { E_CADD = 1, E_BIAS = 2, E_RELU = 4, E_AFF = 8, E_WBF = 16, E_WF32 = 32, E_FINAL = 64 };

#define GRID 256
#define THREADS 512

static __device__ __forceinline__ u16 f2bf(float f) {
  unsigned u = __float_as_uint(f);
  u += 0x7fffu + ((u >> 16) & 1u);
  return (u16)(u >> 16);
}
static __device__ __forceinline__ float bf2f(u16 h) {
  return __uint_as_float(((unsigned)h) << 16);
}

struct MegaArgs {
  const float *nonvis, *fm, *prior, *W1, *b1, *g1, *be1, *m1, *v1;
  const float *W2, *b2, *g2, *be2, *m2, *v2, *Wk, *Uk, *bi, *br;
  const float *ct1w, *ct1b, *ct2w, *ct2b, *ct3w, *ct3b, *ct4w, *ct4b, *Ws, *bs;
  u16 *nonvis_b, *W1nv_t, *W1v_t, *W2t, *Wkt, *Ukt, *Wsnv_t, *Wsv_t;
  u16 *Wp1, *Wp2, *Wp3, *Wp4;
  float *bp1, *bp2, *bp3, *bp4, *scale1, *shift1, *scale2, *shift2, *bs_pad;
  float *P1, *snv, *mx, *mi, *hf;
  u16 *x1, *x2, *hb, *a1, *a2, *a3;
  float *a4, *attn, *vis_sum;
  u16 *visb, *vsb, *fmb;
  float *out;
  unsigned *cnt;
  int use_fmb;
};

// -------- device-scope grid barrier (all 256 blocks co-resident by capacity) --
static __device__ __forceinline__ void gbar(unsigned* cnt, unsigned goal) {
  __syncthreads();
  if (threadIdx.x == 0) {
    __threadfence();            // release: flush this XCD's writes
    atomicAdd(cnt, 1u);
    while (atomicAdd(cnt, 0u) < goal) __builtin_amdgcn_s_sleep(2);
    __threadfence();            // acquire: invalidate stale cached lines
  }
  __syncthreads();
}

// -------- 64x128 MFMA GEMM tile, 8 waves, dbuf LDS + XOR swizzle (T2) --------
template <int FLAGS>
static __device__ void gtile(u16* As, u16* Bs,
    const u16* __restrict__ A, const u16* __restrict__ Bt,
    float* __restrict__ Cf, u16* __restrict__ Cb,
    const float* __restrict__ Cadd, const float* __restrict__ bias,
    const float* __restrict__ scale, const float* __restrict__ shift,
    int N, int K, int bx, int by) {
  const int tid = threadIdx.x;
  const int wave = tid >> 6, lane = tid & 63;
  const int bm = by << 6, bn = bx << 7;
  const int lr = lane & 15, lg = lane >> 4;
  const int rx = lr & 7;
  const int wm = (wave >> 2) << 5, wn = (wave & 3) << 5;

  f32x4 acc[2][2] = {};

  auto stage = [&](int buf, int kt) {
    { const int row = tid >> 3;
      const int cg = (tid & 7) ^ (row & 7);
      __builtin_amdgcn_global_load_lds(
          (gvoid_t*)(A + (size_t)(bm + row) * K + kt + (cg << 3)),
          (lvoid_t*)(As + buf * 4096 + wave * 512), 16, 0, 0); }
#pragma unroll
    for (int i = 0; i < 2; ++i) {
      const int li = i * 512 + tid;
      const int row = li >> 3;
      const int cg = (li & 7) ^ (row & 7);
      __builtin_amdgcn_global_load_lds(
          (gvoid_t*)(Bt + (size_t)(bn + row) * K + kt + (cg << 3)),
          (lvoid_t*)(Bs + buf * 8192 + i * 4096 + wave * 512), 16, 0, 0);
    }
  };

  stage(0, 0);
  int buf = 0;
  for (int kt = 0; kt < K; kt += 64) {
    __syncthreads();                       // buf staged; prev reads done
    if (kt + 64 < K) stage(buf ^ 1, kt + 64);
    const u16* Ab = As + buf * 4096;
    const u16* Bb = Bs + buf * 8192;
#pragma unroll
    for (int kk = 0; kk < 64; kk += 32) {
      bf16x8 av[2], bv[2];
#pragma unroll
      for (int mi2 = 0; mi2 < 2; ++mi2)
        av[mi2] = *(const bf16x8*)(Ab + ((wm + mi2 * 16 + lr) << 6) +
                                   ((((kk >> 3) + lg) ^ rx) << 3));
#pragma unroll
      for (int ni = 0; ni < 2; ++ni)
        bv[ni] = *(const bf16x8*)(Bb + ((wn + ni * 16 + lr) << 6) +
                                  ((((kk >> 3) + lg) ^ rx) << 3));
#pragma unroll
      for (int mi2 = 0; mi2 < 2; ++mi2)
#pragma unroll
        for (int ni = 0; ni < 2; ++ni)
          acc[mi2][ni] = __builtin_amdgcn_mfma_f32_16x16x32_bf16(av[mi2], bv[ni], acc[mi2][ni], 0, 0, 0);
    }
    buf ^= 1;
  }

#pragma unroll
  for (int mi2 = 0; mi2 < 2; ++mi2) {
#pragma unroll
    for (int ni = 0; ni < 2; ++ni) {
      const int col = bn + wn + ni * 16 + lr;
#pragma unroll
      for (int r = 0; r < 4; ++r) {
        const int row = bm + wm + mi2 * 16 + (lg << 2) + r;
        float v = acc[mi2][ni][r];
        if (FLAGS & E_FINAL) {
          // out = v/6 + snv(Cadd) + prior(scale); only cols < 51
          if (col < 51)
            Cf[row * 51 + col] = v * (1.f / 6.f) + Cadd[(row << 7) + col] + scale[row * 51 + col];
        } else {
          if (FLAGS & E_CADD) v += Cadd[(size_t)row * N + col];
          if (FLAGS & E_BIAS) v += bias[col];
          if (FLAGS & E_RELU) v = fmaxf(v, 0.f);
          if (FLAGS & E_AFF) v = v * scale[col] + shift[col];
          if (FLAGS & E_WF32) Cf[(size_t)row * N + col] = v;
          if (FLAGS & E_WBF) Cb[(size_t)row * N + col] = f2bf(v);
        }
      }
    }
  }
  __syncthreads();                         // protect LDS reuse by next job
}

// -------- phase bodies --------
static __device__ void fm_body(const MegaArgs& a, int b, int st) {
  const int d0 = st << 2;
  const float* p = a.fm + (size_t)b * 102400 + d0;
  float s0 = 0, s1 = 0, s2 = 0, s3 = 0;
  for (int pp = 0; pp < 100; ++pp) {
    const float4 v = *(const float4*)(p + pp * 1024);
    if (a.use_fmb) {
      ushort4 u;
      u.x = f2bf(v.x); u.y = f2bf(v.y); u.z = f2bf(v.z); u.w = f2bf(v.w);
      *(ushort4*)(a.fmb + (size_t)b * 102400 + pp * 1024 + d0) = u;
    }
    s0 += v.x; s1 += v.y; s2 += v.z; s3 += v.w;
  }
  const float inv = 1.0f / 100.0f;
  s0 *= inv; s1 *= inv; s2 *= inv; s3 *= inv;
  const int o = (b << 10) + d0;
  float4 m; m.x = s0; m.y = s1; m.z = s2; m.w = s3;
  *(float4*)(a.vis_sum + o) = m;
  ushort4 u; u.x = f2bf(s0); u.y = f2bf(s1); u.z = f2bf(s2); u.w = f2bf(s3);
  *(ushort4*)(a.visb + o) = u;
}

static __device__ void prep_body(const MegaArgs& a, int b, int st, float (*t)[65]) {
  const float* in; u16* out; int ld, k0, K, Nv, kT;
  int bb = b;
  if (bb < 1024)      {            in = a.W1; out = a.W1nv_t; ld = 2048; k0 = 0;    K = 2048; Nv = 2048; kT = 32; }
  else if (bb < 1536) { bb -= 1024; in = a.W1; out = a.W1v_t;  ld = 2048; k0 = 2048; K = 1024; Nv = 2048; kT = 16; }
  else if (bb < 2048) { bb -= 1536; in = a.W2; out = a.W2t;   ld = 1024; k0 = 0;    K = 2048; Nv = 1024; kT = 32; }
  else if (bb < 2816) { bb -= 2048; in = a.Wk; out = a.Wkt;   ld = 3072; k0 = 0;    K = 1024; Nv = 3072; kT = 16; }
  else if (bb < 3584) { bb -= 2816; in = a.Uk; out = a.Ukt;   ld = 3072; k0 = 0;    K = 1024; Nv = 3072; kT = 16; }
  else if (bb < 3648) { bb -= 3584; in = a.Ws; out = a.Wsnv_t; ld = 51;  k0 = 0;    K = 2048; Nv = 51;   kT = 32; }
  else                { bb -= 3648; in = a.Ws; out = a.Wsv_t;  ld = 51;  k0 = 2048; K = 1024; Nv = 51;   kT = 16; }
  const int kt = (bb % kT) << 6, nt = (bb / kT) << 6;
  const int tx = st & 63, ty = st >> 6;
#pragma unroll
  for (int i = 0; i < 16; ++i) {
    const int kl = ty + i * 4;
    const int n = nt + tx;
    t[kl][tx] = (n < Nv) ? in[(size_t)(k0 + kt + kl) * ld + n] : 0.f;
  }
  __syncthreads();
#pragma unroll
  for (int i = 0; i < 16; ++i)
    out[(size_t)(nt + ty + i * 4) * K + kt + tx] = f2bf(t[tx][ty + i * 4]);
}

static __device__ void misc_elem(int i, const MegaArgs& a) {
  if (i < 2097152) a.nonvis_b[i] = f2bf(a.nonvis[i]);
  if (i < 1048576) { a.hf[i] = 0.f; a.hb[i] = 0; }
  if (i < 2048) { float sc = a.g1[i] * rsqrtf(a.v1[i] + 1e-3f); a.scale1[i] = sc; a.shift1[i] = a.be1[i] - a.m1[i] * sc; }
  if (i < 1024) { float sc = a.g2[i] * rsqrtf(a.v2[i] + 1e-3f); a.scale2[i] = sc; a.shift2[i] = a.be2[i] - a.m2[i] * sc; }
  if (i < 128) a.bs_pad[i] = (i < 51) ? a.bs[i] : 0.f;
}

// convT weight packing: even out-pixel p: w[0]*x[p/2-1] + w[2]*x[p/2]; odd: w[1]*x[(p-1)/2]
static __device__ void build_elem(long idx, const MegaArgs& a) {
  const float* w; const float* bin; u16* wp; float* bp; int Si, CI, CO; long base;
  if (idx < 1048576)      { base = 0;       w = a.ct1w; bin = a.ct1b; wp = a.Wp1; bp = a.bp1; Si = 1; CI = 1024; CO = 256; }
  else if (idx < 2097152) { base = 1048576; w = a.ct2w; bin = a.ct2b; wp = a.Wp2; bp = a.bp2; Si = 2; CI = 256;  CO = 64; }
  else if (idx < 3145728) { base = 2097152; w = a.ct3w; bin = a.ct3b; wp = a.Wp3; bp = a.bp3; Si = 4; CI = 64;   CO = 16; }
  else                    { base = 3145728; w = a.ct4w; bin = a.ct4b; wp = a.Wp4; bp = a.bp4; Si = 8; CI = 16;   CO = 1; }
  const long r = idx - base;
  const int n = (int)(r >> 10), k = (int)(r & 1023);
  const int So = Si * 2;
  const int co = n % CO;
  const int pox = (n / CO) % So;
  const int poy = n / (CO * So);
  const int ci = k % CI;
  const int pix = (k / CI) % Si;
  const int piy = k / (CI * Si);
  int wy = -1, wx = -1;
  if (poy & 1) { if (piy == (poy >> 1)) wy = 1; }
  else { if (piy == (poy >> 1)) wy = 2; else if (piy == (poy >> 1) - 1) wy = 0; }
  if (pox & 1) { if (pix == (pox >> 1)) wx = 1; }
  else { if (pix == (pox >> 1)) wx = 2; else if (pix == (pox >> 1) - 1) wx = 0; }
  float v = 0.f;
  if (wy >= 0 && wx >= 0) v = w[((size_t)(wy * 3 + wx) * CI + ci) * CO + co];
  wp[(size_t)n * 1024 + k] = f2bf(v);
  if (k == 0) bp[n] = bin[co];
}

static __device__ void gru_elem(int idx, const MegaArgs& a, int it) {
  const int b = idx >> 10, d = idx & 1023;
  const float* mxb = a.mx + (size_t)b * 3072;
  const float xz = mxb[d], xr = mxb[d + 1024], xh = mxb[d + 2048];
  float iz, ir, ih;
  if (it == 0) { iz = a.br[d]; ir = a.br[d + 1024]; ih = a.br[d + 2048]; }
  else {
    const float* mib = a.mi + (size_t)b * 3072;
    iz = mib[d]; ir = mib[d + 1024]; ih = mib[d + 2048];
  }
  const float zg = 1.f / (1.f + expf(-(xz + iz)));
  const float rg = 1.f / (1.f + expf(-(xr + ir)));
  const float hh = tanhf(xh + rg * ih);
  const float hn = zg * a.hf[idx] + (1.f - zg) * hh;
  a.hf[idx] = hn;
  a.hb[idx] = f2bf(hn);
}

static __device__ __forceinline__ void taps(int o, int& si, float* w) {
  const float s = 1.6f * (float)o + 0.3f;
  int s0 = (int)ceilf(s - 1.6f);
  if (s0 < 0) s0 = 0;
  si = s0;
  float sum = 0.f;
#pragma unroll
  for (int j = 0; j < 4; ++j) {
    const int i = s0 + j;
    float ww = 0.f;
    if (i <= 15) {
      const float d = fabsf(s - (float)i) * (1.0f / 1.6f);
      ww = fmaxf(0.f, 1.f - d);
    }
    w[j] = ww;
    sum += ww;
  }
  const float inv = 1.f / sum;
#pragma unroll
  for (int j = 0; j < 4; ++j) w[j] *= inv;
}

static __device__ void attn_phase(const MegaArgs& a, char* arena) {
  float* sm = (float*)arena;  // 512 floats
  const int tid = threadIdx.x;
  const int g = tid >> 7, gt = tid & 127;
  const int b = blockIdx.x * 4 + g;
  float val = -1e30f;
  if (gt < 100) {
    const int oy = gt / 10, ox = gt - oy * 10;
    int siy, six;
    float wy[4], wx[4];
    taps(oy, siy, wy);
    taps(ox, six, wx);
    const float* p = a.a4 + (b << 8);
    float s = 0.f;
#pragma unroll
    for (int jy = 0; jy < 4; ++jy) {
      const int iy = min(siy + jy, 15);
      float rs = 0.f;
#pragma unroll
      for (int jx = 0; jx < 4; ++jx) {
        const int ix = min(six + jx, 15);
        rs += wx[jx] * p[(iy << 4) + ix];
      }
      s += wy[jy] * rs;
    }
    val = s;
  }
  sm[tid] = val;
  __syncthreads();
  for (int off = 64; off > 0; off >>= 1) {
    if (gt < off) sm[tid] = fmaxf(sm[tid], sm[tid + off]);
    __syncthreads();
  }
  const float mxv = sm[g << 7];
  __syncthreads();
  const float e = (gt < 100) ? expf(val - mxv) : 0.f;
  sm[tid] = e;
  __syncthreads();
  for (int off = 64; off > 0; off >>= 1) {
    if (gt < off) sm[tid] += sm[tid + off];
    __syncthreads();
  }
  if (gt < 100) a.attn[b * 100 + gt] = e / sm[g << 7];
}

static __device__ void wsum_job(const MegaArgs& a, int j, char* arena) {
  float* at = (float*)arena;  // 2 x 128
  const int tid = threadIdx.x;
  const int sub = tid >> 8, st = tid & 255;
  const int b = j * 2 + sub;
  if (st < 100) at[(sub << 7) + st] = a.attn[b * 100 + st];
  __syncthreads();
  const int d0 = st << 2;
  float s0 = 0, s1 = 0, s2 = 0, s3 = 0;
  if (a.use_fmb) {
    const u16* p = a.fmb + (size_t)b * 102400 + d0;
    for (int pp = 0; pp < 100; ++pp) {
      const ushort4 v = *(const ushort4*)(p + pp * 1024);
      const float aa = at[(sub << 7) + pp];
      s0 += aa * bf2f(v.x); s1 += aa * bf2f(v.y); s2 += aa * bf2f(v.z); s3 += aa * bf2f(v.w);
    }
  } else {
    const float* p = a.fm + (size_t)b * 102400 + d0;
    for (int pp = 0; pp < 100; ++pp) {
      const float4 v = *(const float4*)(p + pp * 1024);
      const float aa = at[(sub << 7) + pp];
      s0 += aa * v.x; s1 += aa * v.y; s2 += aa * v.z; s3 += aa * v.w;
    }
  }
  const int o = (b << 10) + d0;
  float4 vs = *(float4*)(a.vis_sum + o);
  vs.x += s0; vs.y += s1; vs.z += s2; vs.w += s3;
  *(float4*)(a.vis_sum + o) = vs;
  ushort4 u; u.x = f2bf(s0); u.y = f2bf(s1); u.z = f2bf(s2); u.w = f2bf(s3);
  *(ushort4*)(a.visb + o) = u;
  ushort4 w; w.x = f2bf(vs.x); w.y = f2bf(vs.y); w.z = f2bf(vs.z); w.w = f2bf(vs.w);
  *(ushort4*)(a.vsb + o) = w;
  __syncthreads();  // at reuse
}

// -------- the mega kernel: whole net, one launch, 52 grid barriers --------
__global__ __launch_bounds__(THREADS) void mega_k(MegaArgs a) {
  __shared__ char arena[49152];
  u16* As = (u16*)arena;
  u16* Bs = (u16*)(arena + 16384);
  const int tid = threadIdx.x;
  const int bid = blockIdx.x;
  unsigned ep = 0;

  // ---- PS1: fm_pass + weight transposes + convT packing + misc ----
  for (int j = bid; j < 3024; j += GRID) {
    if (j < 512) {
      const int sub = tid >> 8, st = tid & 255;
      fm_body(a, j * 2 + sub, st);
    } else if (j < 2352) {
      const int sub = tid >> 8, st = tid & 255;
      prep_body(a, (j - 512) * 2 + sub, st, (float(*)[65])(arena + sub * 16640));
    } else if (j < 2608) {
      const int base = (j - 2352) * 8192;
#pragma unroll
      for (int r = 0; r < 16; ++r) misc_elem(base + r * 512 + tid, a);
    } else {
      const long base = (long)(j - 2608) * 8192;
#pragma unroll
      for (int r = 0; r < 16; ++r) build_elem(base + r * 512 + tid, a);
    }
    __syncthreads();
  }
  ++ep; gbar(a.cnt, ep * GRID);

  // ---- PS2: P1 = nonvis@W1nv + b1 (256 tiles); snv = nonvis@Wsnv + bs (16) ----
  for (int j = bid; j < 272; j += GRID) {
    if (j < 256)
      gtile<E_BIAS | E_WF32>(As, Bs, a.nonvis_b, a.W1nv_t, a.P1, nullptr, nullptr,
                             a.b1, nullptr, nullptr, 2048, 2048, j & 15, j >> 4);
    else
      gtile<E_BIAS | E_WF32>(As, Bs, a.nonvis_b, a.Wsnv_t, a.snv, nullptr, nullptr,
                             a.bs_pad, nullptr, nullptr, 128, 2048, 0, j - 256);
  }
  ++ep; gbar(a.cnt, ep * GRID);

  // ---- 5 iterations ----
  for (int it = 0; it < 5; ++it) {
    // PA: x1 = bn(relu(visb@W1v + P1))
    for (int j = bid; j < 256; j += GRID)
      gtile<E_CADD | E_RELU | E_AFF | E_WBF>(As, Bs, a.visb, a.W1v_t, nullptr, a.x1,
                                             a.P1, nullptr, a.scale1, a.shift1,
                                             2048, 1024, j & 15, j >> 4);
    ++ep; gbar(a.cnt, ep * GRID);
    // PB: x2 = bn(relu(x1@W2 + b2))
    for (int j = bid; j < 128; j += GRID)
      gtile<E_BIAS | E_RELU | E_AFF | E_WBF>(As, Bs, a.x1, a.W2t, nullptr, a.x2,
                                             nullptr, a.b2, a.scale2, a.shift2,
                                             1024, 2048, j & 7, j >> 3);
    ++ep; gbar(a.cnt, ep * GRID);
    // PC: mx = x2@Wk + bi
    for (int j = bid; j < 384; j += GRID)
      gtile<E_BIAS | E_WF32>(As, Bs, a.x2, a.Wkt, a.mx, nullptr, nullptr, a.bi,
                             nullptr, nullptr, 3072, 1024, j % 24, j / 24);
    ++ep; gbar(a.cnt, ep * GRID);
    // PD: gru (it==0: mi == br since h==0)
#pragma unroll
    for (int r = 0; r < 8; ++r) gru_elem(r * 131072 + bid * 512 + tid, a, it);
    ++ep; gbar(a.cnt, ep * GRID);
    // PE: c1 = relu(hb@Wp1 + bp1); plus mi' = hb@Uk + br for next iter
    {
      const int nj = (it < 4) ? 512 : 128;
      for (int j = bid; j < nj; j += GRID) {
        if (j < 128)
          gtile<E_BIAS | E_RELU | E_WBF>(As, Bs, a.hb, a.Wp1, nullptr, a.a1,
                                         nullptr, a.bp1, nullptr, nullptr,
                                         1024, 1024, j & 7, j >> 3);
        else {
          const int t2 = j - 128;
          gtile<E_BIAS | E_WF32>(As, Bs, a.hb, a.Ukt, a.mi, nullptr, nullptr, a.br,
                                 nullptr, nullptr, 3072, 1024, t2 % 24, t2 / 24);
        }
      }
    }
    ++ep; gbar(a.cnt, ep * GRID);
    // PF: c2
    for (int j = bid; j < 128; j += GRID)
      gtile<E_BIAS | E_RELU | E_WBF>(As, Bs, a.a1, a.Wp2, nullptr, a.a2, nullptr,
                                     a.bp2, nullptr, nullptr, 1024, 1024, j & 7, j >> 3);
    ++ep; gbar(a.cnt, ep * GRID);
    // PG: c3
    for (int j = bid; j < 128; j += GRID)
      gtile<E_BIAS | E_RELU | E_WBF>(As, Bs, a.a2, a.Wp3, nullptr, a.a3, nullptr,
                                     a.bp3, nullptr, nullptr, 1024, 1024, j & 7, j >> 3);
    ++ep; gbar(a.cnt, ep * GRID);
    // PH: c4 -> a4 (1024 x 256 fp32)
    for (int j = bid; j < 32; j += GRID)
      gtile<E_BIAS | E_WF32>(As, Bs, a.a3, a.Wp4, a.a4, nullptr, nullptr, a.bp4,
                             nullptr, nullptr, 256, 1024, j & 1, j >> 1);
    ++ep; gbar(a.cnt, ep * GRID);
    // PI: bilinear resize + softmax
    attn_phase(a, arena);
    ++ep; gbar(a.cnt, ep * GRID);
    // PJ: vis = sum_p attn*fm; vis_sum += vis
    for (int j = bid; j < 512; j += GRID) wsum_job(a, j, arena);
    ++ep; gbar(a.cnt, ep * GRID);
  }

  // PZ: out = (vsb@Wsv)/6 + snv + prior  (fused epilogue)
  for (int j = bid; j < 16; j += GRID)
    gtile<E_FINAL>(As, Bs, a.vsb, a.Wsv_t, a.out, nullptr, a.snv, nullptr,
                   a.prior, nullptr, 128, 1024, 0, j);
}

extern "C" void kernel_launch(void* const* d_in, const int* in_sizes, int n_in,
                              void* d_out, int out_size, void* d_ws, size_t ws_size,
                              hipStream_t stream) {
  (void)in_sizes; (void)n_in; (void)out_size;
  MegaArgs a;
  a.nonvis = (const float*)d_in[0];  a.fm   = (const float*)d_in[1];
  a.prior  = (const float*)d_in[2];  a.W1   = (const float*)d_in[3];
  a.b1  = (const float*)d_in[4];     a.g1   = (const float*)d_in[5];
  a.be1 = (const float*)d_in[6];     a.m1   = (const float*)d_in[7];
  a.v1  = (const float*)d_in[8];     a.W2   = (const float*)d_in[9];
  a.b2  = (const float*)d_in[10];    a.g2   = (const float*)d_in[11];
  a.be2 = (const float*)d_in[12];    a.m2   = (const float*)d_in[13];
  a.v2  = (const float*)d_in[14];    a.Wk   = (const float*)d_in[15];
  a.Uk  = (const float*)d_in[16];    a.bi   = (const float*)d_in[17];
  a.br  = (const float*)d_in[18];    a.ct1w = (const float*)d_in[19];
  a.ct1b = (const float*)d_in[20];   a.ct2w = (const float*)d_in[21];
  a.ct2b = (const float*)d_in[22];   a.ct3w = (const float*)d_in[23];
  a.ct3b = (const float*)d_in[24];   a.ct4w = (const float*)d_in[25];
  a.ct4b = (const float*)d_in[26];   a.Ws   = (const float*)d_in[27];
  a.bs  = (const float*)d_in[28];

  char* base = (char*)d_ws;
  size_t off = 0;
  auto alloc = [&](size_t bytes) -> void* {
    void* r = base + off;
    off = (off + bytes + 255) & ~(size_t)255;
    return r;
  };

  a.cnt      = (unsigned*)alloc(256);
  a.nonvis_b = (u16*)alloc(4194304);
  a.W1nv_t   = (u16*)alloc(8388608);
  a.W1v_t    = (u16*)alloc(4194304);
  a.W2t      = (u16*)alloc(4194304);
  a.Wkt      = (u16*)alloc(6291456);
  a.Ukt      = (u16*)alloc(6291456);
  a.Wsnv_t   = (u16*)alloc(524288);
  a.Wsv_t    = (u16*)alloc(262144);
  a.Wp1      = (u16*)alloc(2097152);
  a.Wp2      = (u16*)alloc(2097152);
  a.Wp3      = (u16*)alloc(2097152);
  a.Wp4      = (u16*)alloc(524288);
  a.bp1      = (float*)alloc(4096);
  a.bp2      = (float*)alloc(4096);
  a.bp3      = (float*)alloc(4096);
  a.bp4      = (float*)alloc(1024);
  a.scale1   = (float*)alloc(8192);
  a.shift1   = (float*)alloc(8192);
  a.scale2   = (float*)alloc(4096);
  a.shift2   = (float*)alloc(4096);
  a.bs_pad   = (float*)alloc(512);
  a.P1       = (float*)alloc(8388608);
  a.snv      = (float*)alloc(524288);
  a.x1       = (u16*)alloc(4194304);
  a.x2       = (u16*)alloc(2097152);
  a.mx       = (float*)alloc(12582912);
  a.mi       = (float*)alloc(12582912);
  a.hf       = (float*)alloc(4194304);
  a.hb       = (u16*)alloc(2097152);
  a.a1       = (u16*)alloc(2097152);
  a.a2       = (u16*)alloc(2097152);
  a.a3       = (u16*)alloc(2097152);
  a.a4       = (float*)alloc(1048576);
  a.attn     = (float*)alloc(409600);
  a.vis_sum  = (float*)alloc(4194304);
  a.visb     = (u16*)alloc(2097152);
  a.vsb      = (u16*)alloc(2097152);
  a.out      = (float*)d_out;
  a.fmb = nullptr;
  a.use_fmb = 0;
  if (off + (size_t)209715200 + 256 <= ws_size) {
    a.fmb = (u16*)alloc(209715200);
    a.use_fmb = 1;
  }

  hipMemsetAsync(a.cnt, 0, 8, stream);
  mega_k<<<GRID, THREADS, 0, stream>>>(a);
}